// Round 4
// baseline (103.578 us; speedup 1.0000x reference)
//
#include <hip/hip_runtime.h>
#include <hip/hip_bf16.h>

#define DD 128
#define NCLS 10
#define CHUNK 512
#define KSTEP 32

typedef __attribute__((ext_vector_type(8))) short s16x8;
typedef __attribute__((ext_vector_type(4))) float f32x4;
typedef __attribute__((ext_vector_type(4))) unsigned int u32x4;
typedef __attribute__((ext_vector_type(4))) unsigned short u16x4;

union FU { unsigned u[4]; s16x8 v; };

__device__ inline unsigned short f2bf(float x) {
  union { float f; unsigned u; } c; c.f = x;
  unsigned u = c.u;
  u += 0x7fffu + ((u >> 16) & 1u);   // RNE to bf16
  return (unsigned short)(u >> 16);
}

// ---------------- K0: zero meta + scal (replaces slow rocclr fill) ----------------
__global__ void k_init(int* __restrict__ ws) {
  ws[threadIdx.x] = 0;               // 128 ints = 512 B
}

// ---------------- K1a: labels + class histogram (LDS-staged Pi) ----------------
__global__ void k_label(const float* __restrict__ Pi, int N,
                        unsigned char* __restrict__ label, int* __restrict__ meta) {
  __shared__ float pish[2560];
  __shared__ int h[NCLS];
  int t = threadIdx.x;
  if (t < NCLS) h[t] = 0;
  size_t base4 = (size_t)blockIdx.x * 640;       // in f32x4 units
  size_t tot4 = (size_t)N * NCLS / 4;
  {
    const f32x4* src = (const f32x4*)Pi;
    f32x4* dst = (f32x4*)pish;
    for (int i = t; i < 640; i += 256) {
      size_t gi = base4 + i;
      f32x4 z = {0.f, 0.f, 0.f, 0.f};
      dst[i] = (gi < tot4) ? src[gi] : z;
    }
  }
  __syncthreads();
  int n = blockIdx.x * 256 + t;
  if (n < N) {
    const float* p = &pish[t * NCLS];
    float best = p[0]; int bj = 0;
#pragma unroll
    for (int j = 1; j < NCLS; j++) { float v = p[j]; if (v > best) { best = v; bj = j; } }
    label[n] = (unsigned char)bj;
    atomicAdd(&h[bj], 1);
  }
  __syncthreads();
  if (t < NCLS) atomicAdd(&meta[t], h[t]);
}

// ---------------- K2: prefix over padded counts, init cursors ----------------
// meta: [0..9]=counts  [10..20]=chunkstart(11)  [32..41]=cursors
__global__ void k_prefix(int* meta) {
  if (threadIdx.x == 0) {
    int cs = 0;
    meta[10] = 0;
    for (int j = 0; j < NCLS; j++) {
      int cp = (meta[j] + CHUNK - 1) / CHUNK;
      meta[32 + j] = cs * CHUNK;    // cursor = padded offset
      cs += cp;
      meta[10 + j + 1] = cs;
    }
  }
}

// ---------------- K2b: fill only the per-class pad gaps with -1 ----------------
__global__ void k_padfill(const int* __restrict__ meta, int* __restrict__ perm) {
  int j = blockIdx.x, t = threadIdx.x;          // 10 blocks x 512
  int dstart = meta[10 + j] * CHUNK + meta[j];  // first pad slot
  int dend = meta[11 + j] * CHUNK;              // end of class region
  int idx = dstart + t;
  if (idx < dend) perm[idx] = -1;
}

// ---------------- K1b: block-aggregated counting sort -> perm ----------------
__global__ void k_rank(const unsigned char* __restrict__ label, int N,
                       int* __restrict__ meta, int* __restrict__ perm) {
  __shared__ int h[NCLS];
  __shared__ int base[NCLS];
  int t = threadIdx.x;
  if (t < NCLS) h[t] = 0;
  __syncthreads();
  int n = blockIdx.x * 256 + t;
  int lj = 0, lr = 0;
  bool act = (n < N);
  if (act) { lj = label[n]; lr = atomicAdd(&h[lj], 1); }
  __syncthreads();
  if (t < NCLS) base[t] = atomicAdd(&meta[32 + t], h[t]);
  __syncthreads();
  if (act) perm[base[lj] + lr] = n;
}

// ---------------- K4: gather syrk, pipelined: perm in LDS, reg prefetch, dbuf tile ----
__global__ __launch_bounds__(256) void k_syrk(const float* __restrict__ Z,
                                              const int* __restrict__ perm,
                                              const int* __restrict__ meta,
                                              float* __restrict__ partial) {
  __shared__ int permsh[CHUNK];
  __shared__ __align__(16) char tilec[2][8448];
  int b = blockIdx.x;
  int t = threadIdx.x;
  if (b >= meta[20]) return;
  ((int2*)permsh)[t] = ((const int2*)(perm + (size_t)b * CHUNK))[t];
  int l = t & 63, w = t >> 6;
  int g = l >> 4, m = l & 15;
  int d0 = (w >> 1) * 64, e0 = (w & 1) * 64;
  int sk2 = t >> 4, sq = t & 15;
  f32x4 acc[4][4] = {};
  __syncthreads();

  // prologue: load + convert + store tile 0
  f32x4 cur0, cur1, cur2, cur3;
  {
    int ra = permsh[2 * sk2];
    int rb = permsh[2 * sk2 + 1];
    f32x4 z = {0.f, 0.f, 0.f, 0.f};
    cur0 = z; cur1 = z; cur2 = z; cur3 = z;
    if (ra >= 0) { const float* zp = Z + (size_t)ra * DD + sq * 4;
                   cur0 = *(const f32x4*)zp; cur1 = *(const f32x4*)(zp + 64); }
    if (rb >= 0) { const float* zp = Z + (size_t)rb * DD + sq * 4;
                   cur2 = *(const f32x4*)zp; cur3 = *(const f32x4*)(zp + 64); }
    u32x4 u0, u1;
#pragma unroll
    for (int i = 0; i < 4; i++) {
      u0[i] = (unsigned)f2bf(cur0[i]) | ((unsigned)f2bf(cur2[i]) << 16);
      u1[i] = (unsigned)f2bf(cur1[i]) | ((unsigned)f2bf(cur3[i]) << 16);
    }
    char* tb = tilec[0] + sk2 * 528 + sq * 16;
    *(u32x4*)tb = u0;
    *(u32x4*)(tb + 256) = u1;
  }
  __syncthreads();

  for (int ks = 0; ks < CHUNK / KSTEP; ks++) {
    // issue next iteration's global loads first (prefetch into regs)
    f32x4 nxt0, nxt1, nxt2, nxt3;
    bool more = (ks + 1 < CHUNK / KSTEP);
    if (more) {
      int ra = permsh[(ks + 1) * KSTEP + 2 * sk2];
      int rb = permsh[(ks + 1) * KSTEP + 2 * sk2 + 1];
      f32x4 z = {0.f, 0.f, 0.f, 0.f};
      nxt0 = z; nxt1 = z; nxt2 = z; nxt3 = z;
      if (ra >= 0) { const float* zp = Z + (size_t)ra * DD + sq * 4;
                     nxt0 = *(const f32x4*)zp; nxt1 = *(const f32x4*)(zp + 64); }
      if (rb >= 0) { const float* zp = Z + (size_t)rb * DD + sq * 4;
                     nxt2 = *(const f32x4*)zp; nxt3 = *(const f32x4*)(zp + 64); }
    }
    // compute current tile
    FU A[4], B[4];
    const char* fbase = tilec[ks & 1] + g * (4 * 528) + m * 4;
#pragma unroll
    for (int dt = 0; dt < 4; dt++) {
      const char* p = fbase + (d0 + dt * 16) * 4;
      A[dt].u[0] = *(const unsigned*)(p);
      A[dt].u[1] = *(const unsigned*)(p + 528);
      A[dt].u[2] = *(const unsigned*)(p + 1056);
      A[dt].u[3] = *(const unsigned*)(p + 1584);
    }
    if (d0 != e0) {
#pragma unroll
      for (int et = 0; et < 4; et++) {
        const char* p = fbase + (e0 + et * 16) * 4;
        B[et].u[0] = *(const unsigned*)(p);
        B[et].u[1] = *(const unsigned*)(p + 528);
        B[et].u[2] = *(const unsigned*)(p + 1056);
        B[et].u[3] = *(const unsigned*)(p + 1584);
      }
    } else {
#pragma unroll
      for (int et = 0; et < 4; et++) B[et] = A[et];
    }
#pragma unroll
    for (int dt = 0; dt < 4; dt++)
#pragma unroll
      for (int et = 0; et < 4; et++)
        acc[dt][et] = __builtin_amdgcn_mfma_f32_16x16x32_bf16(A[dt].v, B[et].v, acc[dt][et], 0, 0, 0);
    // convert + store next tile into other buffer
    if (more) {
      u32x4 u0, u1;
#pragma unroll
      for (int i = 0; i < 4; i++) {
        u0[i] = (unsigned)f2bf(nxt0[i]) | ((unsigned)f2bf(nxt2[i]) << 16);
        u1[i] = (unsigned)f2bf(nxt1[i]) | ((unsigned)f2bf(nxt3[i]) << 16);
      }
      char* tb = tilec[(ks + 1) & 1] + sk2 * 528 + sq * 16;
      *(u32x4*)tb = u0;
      *(u32x4*)(tb + 256) = u1;
    }
    __syncthreads();
  }

  float* pb = partial + (size_t)b * 16384;
#pragma unroll
  for (int dt = 0; dt < 4; dt++)
#pragma unroll
    for (int et = 0; et < 4; et++)
#pragma unroll
      for (int r = 0; r < 4; r++)
        pb[(d0 + dt * 16 + g * 4 + r) * DD + (e0 + et * 16 + m)] = acc[dt][et][r];
}

// ---------------- K5: reduce chunk partials -> M[j], Gram, tr(Gram) ----------------
__global__ void k_reduceG(const float* __restrict__ partial, const int* __restrict__ meta,
                          float* __restrict__ M, float* __restrict__ Gram,
                          float* __restrict__ scal) {
  int idx = blockIdx.x * 128 + threadIdx.x;   // 128 blocks x 128
  float tot = 0.f;
#pragma unroll
  for (int j = 0; j < NCLS; j++) {
    int c0 = meta[10 + j], c1 = meta[11 + j];
    float s = 0.f;
#pragma unroll 4
    for (int c = c0; c < c1; c++) s += partial[(size_t)c * 16384 + idx];
    M[(size_t)j * 16384 + idx] = s;
    tot += s;
  }
  Gram[idx] = tot;
  if ((idx >> 7) == (idx & 127)) atomicAdd(&scal[0], tot);
}

// ---------------- K6: makeE (+t1,t2) fused with colnorm ----------------
__global__ __launch_bounds__(256) void k_makeE_cn(const float* __restrict__ Gram,
                                                  const float* __restrict__ Us,
                                                  const int* __restrict__ meta,
                                                  float* __restrict__ scal,
                                                  float* __restrict__ E,
                                                  unsigned short* __restrict__ Ebf,
                                                  float cf, float nf) {
  __shared__ __align__(16) char pool[1024];
  float* red = (float*)pool;
  int b = blockIdx.x, t = threadIdx.x;
  if (b < 64) {
    int idx = b * 256 + t;
    float c = 1.0f + cf * scal[0] * (1.0f / 128.0f);
    float rc = 1.0f / c;
    int dg = ((idx >> 7) == (idx & 127)) ? 1 : 0;
    float e = (cf * rc) * Gram[idx] + (dg ? (rc - 1.0f) : 0.0f);
    E[idx] = e;
    Ebf[idx] = f2bf(e);
    float p1 = dg ? e : 0.0f;
    float p2 = e * e;
#pragma unroll
    for (int o = 32; o; o >>= 1) { p1 += __shfl_down(p1, o); p2 += __shfl_down(p2, o); }
    if ((t & 63) == 0) { red[t >> 6] = p1; red[4 + (t >> 6)] = p2; }
    __syncthreads();
    if (t == 0) {
      atomicAdd(&scal[3], red[0] + red[1] + red[2] + red[3]);
      atomicAdd(&scal[4], red[4] + red[5] + red[6] + red[7]);
    }
  } else {
    int j = b - 64;
    const float* U = Us + (size_t)j * 16384;
    int e = t & 127, half = t >> 7;
    float* cs = (float*)pool;            // 128 floats
    float* red2 = (float*)(pool + 512);
    float acc = 0.0f;
    int d0 = half * 64;
    for (int d2 = d0; d2 < d0 + 64; d2++) { float v = U[d2 * 128 + e]; acc += v * v; }
    if (half == 0) cs[e] = acc;
    __syncthreads();
    float trj = (float)meta[j];
    float term = 0.0f;
    if (half == 1) {
      float tot = cs[e] + acc;
      term = log1pf((256.0f / trj) * tot);
    }
#pragma unroll
    for (int o = 32; o; o >>= 1) term += __shfl_down(term, o);
    if ((t & 63) == 0) red2[t >> 6] = term;
    __syncthreads();
    if (t == 0) atomicAdd(&scal[1], (trj / (2.0f * nf)) * (red2[2] + red2[3]));
  }
}

// ---------------- mm tail: P = X^T Y (symmetric operands), 128x128, one block ----
__device__ __forceinline__ void mm_tail(const unsigned short* __restrict__ Xbf,
                                        const unsigned short* __restrict__ Ybf,
                                        float* __restrict__ Pf,
                                        unsigned short* __restrict__ Pbf,
                                        const float* __restrict__ Tdot,
                                        char* ldsX, char* ldsY, int t,
                                        float& tA, float& tB) {
  int l = t & 63, w = t >> 6;
  int g = l >> 4, m = l & 15;
  int d0 = (w >> 1) * 64, e0 = (w & 1) * 64;
  int sk2 = t >> 4, sq = t & 15;
  bool same = (Xbf == Ybf);
  f32x4 acc[4][4] = {};
  for (int ks = 0; ks < 4; ks++) {
    int k0 = ks * 32 + 2 * sk2;
    __syncthreads();
#pragma unroll
    for (int qi = 0; qi < 2; qi++) {
      int q = sq + qi * 16;
      u16x4 a = *(const u16x4*)(Xbf + k0 * 128 + q * 4);
      u16x4 bb = *(const u16x4*)(Xbf + (k0 + 1) * 128 + q * 4);
      u32x4 u;
#pragma unroll
      for (int i = 0; i < 4; i++) u[i] = (unsigned)a[i] | ((unsigned)bb[i] << 16);
      *(u32x4*)(ldsX + sk2 * 528 + q * 16) = u;
      if (!same) {
        u16x4 c0 = *(const u16x4*)(Ybf + k0 * 128 + q * 4);
        u16x4 d1 = *(const u16x4*)(Ybf + (k0 + 1) * 128 + q * 4);
        u32x4 v;
#pragma unroll
        for (int i = 0; i < 4; i++) v[i] = (unsigned)c0[i] | ((unsigned)d1[i] << 16);
        *(u32x4*)(ldsY + sk2 * 528 + q * 16) = v;
      }
    }
    __syncthreads();
    const char* ldsB = same ? ldsX : ldsY;
    FU A[4], B[4];
    const char* fa = ldsX + g * (4 * 528) + m * 4;
    const char* fb = ldsB + g * (4 * 528) + m * 4;
#pragma unroll
    for (int dt = 0; dt < 4; dt++) {
      const char* p = fa + (d0 + dt * 16) * 4;
      A[dt].u[0] = *(const unsigned*)(p);
      A[dt].u[1] = *(const unsigned*)(p + 528);
      A[dt].u[2] = *(const unsigned*)(p + 1056);
      A[dt].u[3] = *(const unsigned*)(p + 1584);
      const char* p2 = fb + (e0 + dt * 16) * 4;
      B[dt].u[0] = *(const unsigned*)(p2);
      B[dt].u[1] = *(const unsigned*)(p2 + 528);
      B[dt].u[2] = *(const unsigned*)(p2 + 1056);
      B[dt].u[3] = *(const unsigned*)(p2 + 1584);
    }
#pragma unroll
    for (int dt = 0; dt < 4; dt++)
#pragma unroll
      for (int et = 0; et < 4; et++)
        acc[dt][et] = __builtin_amdgcn_mfma_f32_16x16x32_bf16(A[dt].v, B[et].v, acc[dt][et], 0, 0, 0);
  }
  tA = 0.0f; tB = 0.0f;
#pragma unroll
  for (int dt = 0; dt < 4; dt++)
#pragma unroll
    for (int et = 0; et < 4; et++)
#pragma unroll
      for (int r = 0; r < 4; r++) {
        int idx = (d0 + dt * 16 + g * 4 + r) * 128 + (e0 + et * 16 + m);
        float p = acc[dt][et][r];
        if (Pf) Pf[idx] = p;
        if (Pbf) Pbf[idx] = f2bf(p);
        tA += p * Tdot[idx];
        tB += p * p;
      }
}

// ---------------- K7: E2 = E*E (+t3,t4) on block 0; k_reg on blocks 1..640 ----
__global__ __launch_bounds__(256) void k_e2_reg(const unsigned short* __restrict__ Ebf,
                                                const float* __restrict__ E,
                                                float* __restrict__ E2f,
                                                unsigned short* __restrict__ E2bf,
                                                const float* __restrict__ Us,
                                                const float* __restrict__ Mg,
                                                float* __restrict__ scal) {
  __shared__ __align__(16) char pool[17024];
  int b = blockIdx.x, t = threadIdx.x;
  if (b == 0) {
    float tA, tB;
    mm_tail(Ebf, Ebf, E2f, E2bf, E, pool, pool, t, tA, tB);
    float* red = (float*)(pool + 16896);
#pragma unroll
    for (int o = 32; o; o >>= 1) { tA += __shfl_down(tA, o); tB += __shfl_down(tB, o); }
    __syncthreads();
    if ((t & 63) == 0) { red[t >> 6] = tA; red[4 + (t >> 6)] = tB; }
    __syncthreads();
    if (t == 0) {
      atomicAdd(&scal[5], red[0] + red[1] + red[2] + red[3]);
      atomicAdd(&scal[6], red[4] + red[5] + red[6] + red[7]);
    }
  } else {
    int bid = b - 1;                 // 640 = 10 * 64
    int j = bid >> 6, tile = bid & 63;
    int dr = (tile >> 3) << 4, er = (tile & 7) << 4;
    float (*ldsA)[132] = (float(*)[132])pool;
    float (*ldsB)[132] = (float(*)[132])(pool + 8448);
    float* wsum = (float*)(pool + 16896);
    int r = t >> 4, cb = t & 15;
    const float* src = Us + (size_t)j * 16384;
    {
      f32x4 a0 = *(const f32x4*)(src + (dr + r) * 128 + cb * 8);
      f32x4 a1 = *(const f32x4*)(src + (dr + r) * 128 + cb * 8 + 4);
      *(f32x4*)(&ldsA[r][cb * 8]) = a0;
      *(f32x4*)(&ldsA[r][cb * 8 + 4]) = a1;
      f32x4 b0 = *(const f32x4*)(src + (er + r) * 128 + cb * 8);
      f32x4 b1 = *(const f32x4*)(src + (er + r) * 128 + cb * 8 + 4);
      *(f32x4*)(&ldsB[r][cb * 8]) = b0;
      *(f32x4*)(&ldsB[r][cb * 8 + 4]) = b1;
    }
    __syncthreads();
    int dd = t >> 4, ee = t & 15;
    const f32x4* rA = (const f32x4*)(&ldsA[dd][0]);
    const f32x4* rB = (const f32x4*)(&ldsB[ee][0]);
    f32x4 s4 = {0.f, 0.f, 0.f, 0.f};
#pragma unroll
    for (int k4 = 0; k4 < 32; k4++) s4 += rA[k4] * rB[k4];
    float acc = s4[0] + s4[1] + s4[2] + s4[3];
    float mval = Mg[(size_t)j * 16384 + (dr + dd) * 128 + (er + ee)];
    float v = mval - acc;
    float sq = v * v;
#pragma unroll
    for (int o = 32; o; o >>= 1) sq += __shfl_down(sq, o);
    if ((t & 63) == 0) wsum[t >> 6] = sq;
    __syncthreads();
    if (t == 0) atomicAdd(&scal[2], wsum[0] + wsum[1] + wsum[2] + wsum[3]);
  }
}

// ---------------- K8: E3 = E*E2 traces (t5,t6) + finalize ----------------
__global__ __launch_bounds__(256) void k_e3_final(const unsigned short* __restrict__ Ebf,
                                                  const unsigned short* __restrict__ E2bf,
                                                  const float* __restrict__ E2f,
                                                  const float* __restrict__ scal,
                                                  float* __restrict__ out, float cf) {
  __shared__ __align__(16) char pool[17024];
  int t = threadIdx.x;
  float tA, tB;
  mm_tail(Ebf, E2bf, (float*)nullptr, (unsigned short*)nullptr, E2f,
          pool, pool + 8448, t, tA, tB);
  float* red = (float*)(pool + 16896);
#pragma unroll
  for (int o = 32; o; o >>= 1) { tA += __shfl_down(tA, o); tB += __shfl_down(tB, o); }
  __syncthreads();
  if ((t & 63) == 0) { red[t >> 6] = tA; red[4 + (t >> 6)] = tB; }
  __syncthreads();
  if (t == 0) {
    float t5 = red[0] + red[1] + red[2] + red[3];
    float t6 = red[4] + red[5] + red[6] + red[7];
    float c = 1.0f + cf * scal[0] * (1.0f / 128.0f);
    float t1 = scal[3], t2 = scal[4], t3 = scal[5], t4 = scal[6];
    float logdet = 128.0f * logf(c) + t1 - 0.5f * t2 + t3 * (1.0f / 3.0f)
                 - 0.25f * t4 + t5 * 0.2f - t6 * (1.0f / 6.0f);
    float R = 0.5f * logdet;
    float Rc = scal[1];
    float reg = 0.5f * scal[2];
    out[0] = -(R - Rc - reg);
    out[1] = R;
    out[2] = Rc;
    out[3] = reg;
  }
}

extern "C" void kernel_launch(void* const* d_in, const int* in_sizes, int n_in,
                              void* d_out, int out_size, void* d_ws, size_t ws_size,
                              hipStream_t stream) {
  const float* Z = (const float*)d_in[0];
  const float* Pi = (const float*)d_in[1];
  const float* Us = (const float*)d_in[2];
  float* out = (float*)d_out;
  int N = in_sizes[0] / DD;
  int NPAD = N + NCLS * CHUNK;
  int MC = (N + CHUNK - 1) / CHUNK + NCLS;
  float cf = (float)DD / ((float)N * 0.5f);   // d/(n*eps)

  char* ws = (char*)d_ws;
  int* meta = (int*)ws;                       // 64 ints
  float* scal = (float*)(ws + 256);           // 16 floats
  int* perm = (int*)(ws + 512);
  size_t off = 512 + (size_t)NPAD * 4;
  off = (off + 511) & ~511ull;
  unsigned char* label = (unsigned char*)(ws + off);
  off += (size_t)N; off = (off + 511) & ~511ull;
  float* M = (float*)(ws + off); off += (size_t)NCLS * 16384 * 4;
  float* Gram = (float*)(ws + off); off += (size_t)16384 * 4;
  float* E = (float*)(ws + off); off += (size_t)16384 * 4;
  float* E2f = (float*)(ws + off); off += (size_t)16384 * 4;
  unsigned short* Ebf = (unsigned short*)(ws + off); off += (size_t)16384 * 2;
  unsigned short* E2bf = (unsigned short*)(ws + off); off += (size_t)16384 * 2;
  off = (off + 511) & ~511ull;
  float* partial = (float*)(ws + off); off += (size_t)MC * 16384 * 4;

  int nb = (N + 255) / 256;
  k_init<<<1, 128, 0, stream>>>((int*)ws);
  k_label<<<nb, 256, 0, stream>>>(Pi, N, label, meta);
  k_prefix<<<1, 32, 0, stream>>>(meta);
  k_padfill<<<NCLS, CHUNK, 0, stream>>>(meta, perm);
  k_rank<<<nb, 256, 0, stream>>>(label, N, meta, perm);
  k_syrk<<<MC, 256, 0, stream>>>(Z, perm, meta, partial);
  k_reduceG<<<128, 128, 0, stream>>>(partial, meta, M, Gram, scal);
  k_makeE_cn<<<74, 256, 0, stream>>>(Gram, Us, meta, scal, E, Ebf, cf, (float)N);
  k_e2_reg<<<641, 256, 0, stream>>>(Ebf, E, E2f, E2bf, Us, M, scal);
  k_e3_final<<<1, 256, 0, stream>>>(Ebf, E2bf, E2f, scal, out, cf);
}

// Round 5
// 102.885 us; speedup vs baseline: 1.0067x; 1.0067x over previous
//
#include <hip/hip_runtime.h>
#include <hip/hip_bf16.h>

#define DD 128
#define NCLS 10
#define CHUNK 256
#define KSTEP 32
#define NIT (CHUNK / KSTEP)

typedef __attribute__((ext_vector_type(8))) short s16x8;
typedef __attribute__((ext_vector_type(4))) float f32x4;
typedef __attribute__((ext_vector_type(4))) unsigned int u32x4;
typedef __attribute__((ext_vector_type(4))) unsigned short u16x4;

union FU { unsigned u[4]; s16x8 v; };

__device__ inline unsigned short f2bf(float x) {
  union { float f; unsigned u; } c; c.f = x;
  unsigned u = c.u;
  u += 0x7fffu + ((u >> 16) & 1u);   // RNE to bf16
  return (unsigned short)(u >> 16);
}

// ---------------- K0: zero meta+scal (128 ints) and Gram (16384 f32) ----------------
__global__ void k_init(int* __restrict__ ws32, float* __restrict__ Gram) {
  int idx = blockIdx.x * 256 + threadIdx.x;    // 64 blocks
  Gram[idx] = 0.0f;
  if (idx < 128) ws32[idx] = 0;
}

// ---------------- K1a: labels + class histogram (LDS-staged Pi) ----------------
__global__ void k_label(const float* __restrict__ Pi, int N,
                        unsigned char* __restrict__ label, int* __restrict__ meta) {
  __shared__ float pish[2560];
  __shared__ int h[NCLS];
  int t = threadIdx.x;
  if (t < NCLS) h[t] = 0;
  size_t base4 = (size_t)blockIdx.x * 640;       // in f32x4 units
  size_t tot4 = (size_t)N * NCLS / 4;
  {
    const f32x4* src = (const f32x4*)Pi;
    f32x4* dst = (f32x4*)pish;
    for (int i = t; i < 640; i += 256) {
      size_t gi = base4 + i;
      f32x4 z = {0.f, 0.f, 0.f, 0.f};
      dst[i] = (gi < tot4) ? src[gi] : z;
    }
  }
  __syncthreads();
  int n = blockIdx.x * 256 + t;
  if (n < N) {
    const float* p = &pish[t * NCLS];
    float best = p[0]; int bj = 0;
#pragma unroll
    for (int j = 1; j < NCLS; j++) { float v = p[j]; if (v > best) { best = v; bj = j; } }
    label[n] = (unsigned char)bj;
    atomicAdd(&h[bj], 1);
  }
  __syncthreads();
  if (t < NCLS) atomicAdd(&meta[t], h[t]);
}

// ---------------- K2: prefix over padded counts, init cursors ----------------
// meta: [0..9]=counts  [10..20]=chunkstart(11)  [32..41]=cursors
__global__ void k_prefix(int* meta) {
  if (threadIdx.x == 0) {
    int cs = 0;
    meta[10] = 0;
    for (int j = 0; j < NCLS; j++) {
      int cp = (meta[j] + CHUNK - 1) / CHUNK;
      meta[32 + j] = cs * CHUNK;    // cursor = padded offset
      cs += cp;
      meta[10 + j + 1] = cs;
    }
  }
}

// ---------------- K1b: counting sort -> perm; tail blocks fill pad gaps ----------------
__global__ void k_rank(const unsigned char* __restrict__ label, int N, int nb,
                       int* __restrict__ meta, int* __restrict__ perm) {
  int bb = blockIdx.x;
  int t = threadIdx.x;
  if (bb >= nb) {                              // pad-fill blocks (one per class)
    int j = bb - nb;
    int dstart = meta[10 + j] * CHUNK + meta[j];
    int dend = meta[11 + j] * CHUNK;
    int idx = dstart + t;
    if (idx < dend) perm[idx] = -1;
    return;
  }
  __shared__ int h[NCLS];
  __shared__ int base[NCLS];
  if (t < NCLS) h[t] = 0;
  __syncthreads();
  int n = bb * 256 + t;
  int lj = 0, lr = 0;
  bool act = (n < N);
  if (act) { lj = label[n]; lr = atomicAdd(&h[lj], 1); }
  __syncthreads();
  if (t < NCLS) base[t] = atomicAdd(&meta[32 + t], h[t]);
  __syncthreads();
  if (act) perm[base[lj] + lr] = n;
}

// ---------------- K4: gather syrk, depth-2 reg prefetch, dbuf LDS, 2 blocks/CU ----
__global__ __launch_bounds__(256, 2) void k_syrk(const float* __restrict__ Z,
                                                 const int* __restrict__ perm,
                                                 const int* __restrict__ meta,
                                                 float* __restrict__ partial) {
  __shared__ int permsh[CHUNK];
  __shared__ __align__(16) char tilec[2][8448];
  int b = blockIdx.x;
  int t = threadIdx.x;
  if (b >= meta[20]) return;
  permsh[t] = perm[(size_t)b * CHUNK + t];
  int l = t & 63, w = t >> 6;
  int g = l >> 4, m = l & 15;
  int d0 = (w >> 1) * 64, e0 = (w & 1) * 64;
  int sk2 = t >> 4, sq = t & 15;
  f32x4 acc[4][4] = {};
  __syncthreads();

  f32x4 A0[4], A1[4];     // two prefetch sets

  auto LOAD = [&](f32x4* R, int ks) {
    int ra = permsh[ks * KSTEP + 2 * sk2];
    int rb = permsh[ks * KSTEP + 2 * sk2 + 1];
    f32x4 z = {0.f, 0.f, 0.f, 0.f};
    R[0] = z; R[1] = z; R[2] = z; R[3] = z;
    if (ra >= 0) { const float* zp = Z + (size_t)ra * DD + sq * 4;
                   R[0] = *(const f32x4*)zp; R[1] = *(const f32x4*)(zp + 64); }
    if (rb >= 0) { const float* zp = Z + (size_t)rb * DD + sq * 4;
                   R[2] = *(const f32x4*)zp; R[3] = *(const f32x4*)(zp + 64); }
  };
  auto STORE = [&](const f32x4* R, int buf) {
    u32x4 u0, u1;
#pragma unroll
    for (int i = 0; i < 4; i++) {
      u0[i] = (unsigned)f2bf(R[0][i]) | ((unsigned)f2bf(R[2][i]) << 16);
      u1[i] = (unsigned)f2bf(R[1][i]) | ((unsigned)f2bf(R[3][i]) << 16);
    }
    char* tb = tilec[buf] + sk2 * 528 + sq * 16;
    *(u32x4*)tb = u0;
    *(u32x4*)(tb + 256) = u1;
  };
  auto COMPUTE = [&](int buf) {
    FU A[4], B[4];
    const char* fbase = tilec[buf] + g * (4 * 528) + m * 4;
#pragma unroll
    for (int dt = 0; dt < 4; dt++) {
      const char* p = fbase + (d0 + dt * 16) * 4;
      A[dt].u[0] = *(const unsigned*)(p);
      A[dt].u[1] = *(const unsigned*)(p + 528);
      A[dt].u[2] = *(const unsigned*)(p + 1056);
      A[dt].u[3] = *(const unsigned*)(p + 1584);
    }
    if (d0 != e0) {
#pragma unroll
      for (int et = 0; et < 4; et++) {
        const char* p = fbase + (e0 + et * 16) * 4;
        B[et].u[0] = *(const unsigned*)(p);
        B[et].u[1] = *(const unsigned*)(p + 528);
        B[et].u[2] = *(const unsigned*)(p + 1056);
        B[et].u[3] = *(const unsigned*)(p + 1584);
      }
    } else {
#pragma unroll
      for (int et = 0; et < 4; et++) B[et] = A[et];
    }
#pragma unroll
    for (int dt = 0; dt < 4; dt++)
#pragma unroll
      for (int et = 0; et < 4; et++)
        acc[dt][et] = __builtin_amdgcn_mfma_f32_16x16x32_bf16(A[dt].v, B[et].v, acc[dt][et], 0, 0, 0);
  };

  LOAD(A0, 0);
  LOAD(A1, 1);
  STORE(A0, 0);
  __syncthreads();
#pragma unroll
  for (int ks = 0; ks < NIT; ks++) {
    if (ks + 2 < NIT) {               // prefetch 2 ahead into the freed set
      if (ks & 1) LOAD(A1, ks + 2); else LOAD(A0, ks + 2);
    }
    COMPUTE(ks & 1);
    if (ks + 1 < NIT) {               // convert+store next tile into other buffer
      if (ks & 1) STORE(A0, (ks + 1) & 1); else STORE(A1, (ks + 1) & 1);
    }
    __syncthreads();
  }

  float* pb = partial + (size_t)b * 16384;
#pragma unroll
  for (int dt = 0; dt < 4; dt++)
#pragma unroll
    for (int et = 0; et < 4; et++)
#pragma unroll
      for (int r = 0; r < 4; r++)
        pb[(d0 + dt * 16 + g * 4 + r) * DD + (e0 + et * 16 + m)] = acc[dt][et][r];
}

// ---------------- K5: reduce chunk partials -> M[j]; Gram via atomics ----------------
__global__ void k_reduceG(const float* __restrict__ partial, const int* __restrict__ meta,
                          float* __restrict__ M, float* __restrict__ Gram,
                          float* __restrict__ scal) {
  int gid = blockIdx.x * 256 + threadIdx.x;   // 640 blocks x 256 = 163840
  int j = gid >> 14;
  int idx = gid & 16383;
  int c0 = meta[10 + j], c1 = meta[11 + j];
  float s = 0.0f;
#pragma unroll 4
  for (int c = c0; c < c1; c++) s += partial[(size_t)c * 16384 + idx];
  M[(size_t)j * 16384 + idx] = s;
  atomicAdd(&Gram[idx], s);
  if ((idx >> 7) == (idx & 127)) atomicAdd(&scal[0], s);
}

// ---------------- K6: makeE (+t1,t2) fused with colnorm ----------------
__global__ __launch_bounds__(256) void k_makeE_cn(const float* __restrict__ Gram,
                                                  const float* __restrict__ Us,
                                                  const int* __restrict__ meta,
                                                  float* __restrict__ scal,
                                                  float* __restrict__ E,
                                                  unsigned short* __restrict__ Ebf,
                                                  float cf, float nf) {
  __shared__ __align__(16) char pool[1024];
  float* red = (float*)pool;
  int b = blockIdx.x, t = threadIdx.x;
  if (b < 64) {
    int idx = b * 256 + t;
    float c = 1.0f + cf * scal[0] * (1.0f / 128.0f);
    float rc = 1.0f / c;
    int dg = ((idx >> 7) == (idx & 127)) ? 1 : 0;
    float e = (cf * rc) * Gram[idx] + (dg ? (rc - 1.0f) : 0.0f);
    E[idx] = e;
    Ebf[idx] = f2bf(e);
    float p1 = dg ? e : 0.0f;
    float p2 = e * e;
#pragma unroll
    for (int o = 32; o; o >>= 1) { p1 += __shfl_down(p1, o); p2 += __shfl_down(p2, o); }
    if ((t & 63) == 0) { red[t >> 6] = p1; red[4 + (t >> 6)] = p2; }
    __syncthreads();
    if (t == 0) {
      atomicAdd(&scal[3], red[0] + red[1] + red[2] + red[3]);
      atomicAdd(&scal[4], red[4] + red[5] + red[6] + red[7]);
    }
  } else {
    int j = b - 64;
    const float* U = Us + (size_t)j * 16384;
    int e = t & 127, half = t >> 7;
    float* cs = (float*)pool;            // 128 floats
    float* red2 = (float*)(pool + 512);
    float acc = 0.0f;
    int d0 = half * 64;
    for (int d2 = d0; d2 < d0 + 64; d2++) { float v = U[d2 * 128 + e]; acc += v * v; }
    if (half == 0) cs[e] = acc;
    __syncthreads();
    float trj = (float)meta[j];
    float term = 0.0f;
    if (half == 1) {
      float tot = cs[e] + acc;
      term = log1pf((256.0f / trj) * tot);
    }
#pragma unroll
    for (int o = 32; o; o >>= 1) term += __shfl_down(term, o);
    if ((t & 63) == 0) red2[t >> 6] = term;
    __syncthreads();
    if (t == 0) atomicAdd(&scal[1], (trj / (2.0f * nf)) * (red2[2] + red2[3]));
  }
}

// ---------------- mm tail: P = X^T Y (symmetric operands), 128x128, one block ----
__device__ __forceinline__ void mm_tail(const unsigned short* __restrict__ Xbf,
                                        const unsigned short* __restrict__ Ybf,
                                        float* __restrict__ Pf,
                                        unsigned short* __restrict__ Pbf,
                                        const float* __restrict__ Tdot,
                                        char* ldsX, char* ldsY, int t,
                                        float& tA, float& tB) {
  int l = t & 63, w = t >> 6;
  int g = l >> 4, m = l & 15;
  int d0 = (w >> 1) * 64, e0 = (w & 1) * 64;
  int sk2 = t >> 4, sq = t & 15;
  bool same = (Xbf == Ybf);
  f32x4 acc[4][4] = {};
  for (int ks = 0; ks < 4; ks++) {
    int k0 = ks * 32 + 2 * sk2;
    __syncthreads();
#pragma unroll
    for (int qi = 0; qi < 2; qi++) {
      int q = sq + qi * 16;
      u16x4 a = *(const u16x4*)(Xbf + k0 * 128 + q * 4);
      u16x4 bb = *(const u16x4*)(Xbf + (k0 + 1) * 128 + q * 4);
      u32x4 u;
#pragma unroll
      for (int i = 0; i < 4; i++) u[i] = (unsigned)a[i] | ((unsigned)bb[i] << 16);
      *(u32x4*)(ldsX + sk2 * 528 + q * 16) = u;
      if (!same) {
        u16x4 c0 = *(const u16x4*)(Ybf + k0 * 128 + q * 4);
        u16x4 d1 = *(const u16x4*)(Ybf + (k0 + 1) * 128 + q * 4);
        u32x4 v;
#pragma unroll
        for (int i = 0; i < 4; i++) v[i] = (unsigned)c0[i] | ((unsigned)d1[i] << 16);
        *(u32x4*)(ldsY + sk2 * 528 + q * 16) = v;
      }
    }
    __syncthreads();
    const char* ldsB = same ? ldsX : ldsY;
    FU A[4], B[4];
    const char* fa = ldsX + g * (4 * 528) + m * 4;
    const char* fb = ldsB + g * (4 * 528) + m * 4;
#pragma unroll
    for (int dt = 0; dt < 4; dt++) {
      const char* p = fa + (d0 + dt * 16) * 4;
      A[dt].u[0] = *(const unsigned*)(p);
      A[dt].u[1] = *(const unsigned*)(p + 528);
      A[dt].u[2] = *(const unsigned*)(p + 1056);
      A[dt].u[3] = *(const unsigned*)(p + 1584);
      const char* p2 = fb + (e0 + dt * 16) * 4;
      B[dt].u[0] = *(const unsigned*)(p2);
      B[dt].u[1] = *(const unsigned*)(p2 + 528);
      B[dt].u[2] = *(const unsigned*)(p2 + 1056);
      B[dt].u[3] = *(const unsigned*)(p2 + 1584);
    }
#pragma unroll
    for (int dt = 0; dt < 4; dt++)
#pragma unroll
      for (int et = 0; et < 4; et++)
        acc[dt][et] = __builtin_amdgcn_mfma_f32_16x16x32_bf16(A[dt].v, B[et].v, acc[dt][et], 0, 0, 0);
  }
  tA = 0.0f; tB = 0.0f;
#pragma unroll
  for (int dt = 0; dt < 4; dt++)
#pragma unroll
    for (int et = 0; et < 4; et++)
#pragma unroll
      for (int r = 0; r < 4; r++) {
        int idx = (d0 + dt * 16 + g * 4 + r) * 128 + (e0 + et * 16 + m);
        float p = acc[dt][et][r];
        if (Pf) Pf[idx] = p;
        if (Pbf) Pbf[idx] = f2bf(p);
        tA += p * Tdot[idx];
        tB += p * p;
      }
}

// ---------------- K7: E2 = E*E (+t3,t4) on block 0; k_reg on blocks 1..640 ----
__global__ __launch_bounds__(256) void k_e2_reg(const unsigned short* __restrict__ Ebf,
                                                const float* __restrict__ E,
                                                float* __restrict__ E2f,
                                                unsigned short* __restrict__ E2bf,
                                                const float* __restrict__ Us,
                                                const float* __restrict__ Mg,
                                                float* __restrict__ scal) {
  __shared__ __align__(16) char pool[17024];
  int b = blockIdx.x, t = threadIdx.x;
  if (b == 0) {
    float tA, tB;
    mm_tail(Ebf, Ebf, E2f, E2bf, E, pool, pool, t, tA, tB);
    float* red = (float*)(pool + 16896);
#pragma unroll
    for (int o = 32; o; o >>= 1) { tA += __shfl_down(tA, o); tB += __shfl_down(tB, o); }
    __syncthreads();
    if ((t & 63) == 0) { red[t >> 6] = tA; red[4 + (t >> 6)] = tB; }
    __syncthreads();
    if (t == 0) {
      atomicAdd(&scal[5], red[0] + red[1] + red[2] + red[3]);
      atomicAdd(&scal[6], red[4] + red[5] + red[6] + red[7]);
    }
  } else {
    int bid = b - 1;                 // 640 = 10 * 64
    int j = bid >> 6, tile = bid & 63;
    int dr = (tile >> 3) << 4, er = (tile & 7) << 4;
    float (*ldsA)[132] = (float(*)[132])pool;
    float (*ldsB)[132] = (float(*)[132])(pool + 8448);
    float* wsum = (float*)(pool + 16896);
    int r = t >> 4, cb = t & 15;
    const float* src = Us + (size_t)j * 16384;
    {
      f32x4 a0 = *(const f32x4*)(src + (dr + r) * 128 + cb * 8);
      f32x4 a1 = *(const f32x4*)(src + (dr + r) * 128 + cb * 8 + 4);
      *(f32x4*)(&ldsA[r][cb * 8]) = a0;
      *(f32x4*)(&ldsA[r][cb * 8 + 4]) = a1;
      f32x4 b0 = *(const f32x4*)(src + (er + r) * 128 + cb * 8);
      f32x4 b1 = *(const f32x4*)(src + (er + r) * 128 + cb * 8 + 4);
      *(f32x4*)(&ldsB[r][cb * 8]) = b0;
      *(f32x4*)(&ldsB[r][cb * 8 + 4]) = b1;
    }
    __syncthreads();
    int dd = t >> 4, ee = t & 15;
    const f32x4* rA = (const f32x4*)(&ldsA[dd][0]);
    const f32x4* rB = (const f32x4*)(&ldsB[ee][0]);
    f32x4 s4 = {0.f, 0.f, 0.f, 0.f};
#pragma unroll
    for (int k4 = 0; k4 < 32; k4++) s4 += rA[k4] * rB[k4];
    float acc = s4[0] + s4[1] + s4[2] + s4[3];
    float mval = Mg[(size_t)j * 16384 + (dr + dd) * 128 + (er + ee)];
    float v = mval - acc;
    float sq = v * v;
#pragma unroll
    for (int o = 32; o; o >>= 1) sq += __shfl_down(sq, o);
    if ((t & 63) == 0) wsum[t >> 6] = sq;
    __syncthreads();
    if (t == 0) atomicAdd(&scal[2], wsum[0] + wsum[1] + wsum[2] + wsum[3]);
  }
}

// ---------------- K8: E3 = E*E2 traces (t5,t6) + finalize ----------------
__global__ __launch_bounds__(256) void k_e3_final(const unsigned short* __restrict__ Ebf,
                                                  const unsigned short* __restrict__ E2bf,
                                                  const float* __restrict__ E2f,
                                                  const float* __restrict__ scal,
                                                  float* __restrict__ out, float cf) {
  __shared__ __align__(16) char pool[17024];
  int t = threadIdx.x;
  float tA, tB;
  mm_tail(Ebf, E2bf, (float*)nullptr, (unsigned short*)nullptr, E2f,
          pool, pool + 8448, t, tA, tB);
  float* red = (float*)(pool + 16896);
#pragma unroll
  for (int o = 32; o; o >>= 1) { tA += __shfl_down(tA, o); tB += __shfl_down(tB, o); }
  __syncthreads();
  if ((t & 63) == 0) { red[t >> 6] = tA; red[4 + (t >> 6)] = tB; }
  __syncthreads();
  if (t == 0) {
    float t5 = red[0] + red[1] + red[2] + red[3];
    float t6 = red[4] + red[5] + red[6] + red[7];
    float c = 1.0f + cf * scal[0] * (1.0f / 128.0f);
    float t1 = scal[3], t2 = scal[4], t3 = scal[5], t4 = scal[6];
    float logdet = 128.0f * logf(c) + t1 - 0.5f * t2 + t3 * (1.0f / 3.0f)
                 - 0.25f * t4 + t5 * 0.2f - t6 * (1.0f / 6.0f);
    float R = 0.5f * logdet;
    float Rc = scal[1];
    float reg = 0.5f * scal[2];
    out[0] = -(R - Rc - reg);
    out[1] = R;
    out[2] = Rc;
    out[3] = reg;
  }
}

extern "C" void kernel_launch(void* const* d_in, const int* in_sizes, int n_in,
                              void* d_out, int out_size, void* d_ws, size_t ws_size,
                              hipStream_t stream) {
  const float* Z = (const float*)d_in[0];
  const float* Pi = (const float*)d_in[1];
  const float* Us = (const float*)d_in[2];
  float* out = (float*)d_out;
  int N = in_sizes[0] / DD;
  int NPAD = N + NCLS * CHUNK;
  int MC = (N + CHUNK - 1) / CHUNK + NCLS;
  float cf = (float)DD / ((float)N * 0.5f);   // d/(n*eps)

  char* ws = (char*)d_ws;
  int* meta = (int*)ws;                       // 64 ints
  float* scal = (float*)(ws + 256);           // 16 floats
  int* perm = (int*)(ws + 512);
  size_t off = 512 + (size_t)NPAD * 4;
  off = (off + 511) & ~511ull;
  unsigned char* label = (unsigned char*)(ws + off);
  off += (size_t)N; off = (off + 511) & ~511ull;
  float* M = (float*)(ws + off); off += (size_t)NCLS * 16384 * 4;
  float* Gram = (float*)(ws + off); off += (size_t)16384 * 4;
  float* E = (float*)(ws + off); off += (size_t)16384 * 4;
  float* E2f = (float*)(ws + off); off += (size_t)16384 * 4;
  unsigned short* Ebf = (unsigned short*)(ws + off); off += (size_t)16384 * 2;
  unsigned short* E2bf = (unsigned short*)(ws + off); off += (size_t)16384 * 2;
  off = (off + 511) & ~511ull;
  float* partial = (float*)(ws + off); off += (size_t)MC * 16384 * 4;

  int nb = (N + 255) / 256;
  k_init<<<64, 256, 0, stream>>>((int*)ws, Gram);
  k_label<<<nb, 256, 0, stream>>>(Pi, N, label, meta);
  k_prefix<<<1, 32, 0, stream>>>(meta);
  k_rank<<<nb + NCLS, 256, 0, stream>>>(label, N, nb, meta, perm);
  k_syrk<<<MC, 256, 0, stream>>>(Z, perm, meta, partial);
  k_reduceG<<<640, 256, 0, stream>>>(partial, meta, M, Gram, scal);
  k_makeE_cn<<<74, 256, 0, stream>>>(Gram, Us, meta, scal, E, Ebf, cf, (float)N);
  k_e2_reg<<<641, 256, 0, stream>>>(Ebf, E, E2f, E2bf, Us, M, scal);
  k_e3_final<<<1, 256, 0, stream>>>(Ebf, E2bf, E2f, scal, out, cf);
}